// Round 1
// baseline (163.022 us; speedup 1.0000x reference)
//
#include <hip/hip_runtime.h>

// 5-layer MLP: 30 -> 64 -> 32 -> 16 -> 8 -> 2, ReLU between layers (not after last).
// One thread per row; all layers fused in registers; weights via scalar loads.

#define D0 30
#define D1 64
#define D2 32
#define D3 16
#define D4 8
#define D5 2

__global__ __launch_bounds__(256) void mlp_fused_kernel(
    const float* __restrict__ x,
    const float* __restrict__ w1, const float* __restrict__ b1,
    const float* __restrict__ w2, const float* __restrict__ b2,
    const float* __restrict__ w3, const float* __restrict__ b3,
    const float* __restrict__ w4, const float* __restrict__ b4,
    const float* __restrict__ w5, const float* __restrict__ b5,
    float* __restrict__ out, int n)
{
    const int row = blockIdx.x * blockDim.x + threadIdx.x;
    if (row >= n) return;

    // Load input row (30 floats = 120 B; 120 % 8 == 0 so float2-aligned for every row).
    float xr[D0];
    const float* xp = x + (long long)row * D0;
    #pragma unroll
    for (int i = 0; i < D0 / 2; ++i) {
        float2 v = *reinterpret_cast<const float2*>(xp + 2 * i);
        xr[2 * i] = v.x;
        xr[2 * i + 1] = v.y;
    }

    // Layer 1: 30 -> 64, ReLU
    float h1[D1];
    #pragma unroll
    for (int j = 0; j < D1; ++j) {
        float acc = b1[j];
        #pragma unroll
        for (int k = 0; k < D0; ++k)
            acc = fmaf(xr[k], w1[j * D0 + k], acc);
        h1[j] = fmaxf(acc, 0.0f);
    }

    // Layer 2: 64 -> 32, ReLU
    float h2[D2];
    #pragma unroll
    for (int j = 0; j < D2; ++j) {
        float acc = b2[j];
        #pragma unroll
        for (int k = 0; k < D1; ++k)
            acc = fmaf(h1[k], w2[j * D1 + k], acc);
        h2[j] = fmaxf(acc, 0.0f);
    }

    // Layer 3: 32 -> 16, ReLU
    float h3[D3];
    #pragma unroll
    for (int j = 0; j < D3; ++j) {
        float acc = b3[j];
        #pragma unroll
        for (int k = 0; k < D2; ++k)
            acc = fmaf(h2[k], w3[j * D2 + k], acc);
        h3[j] = fmaxf(acc, 0.0f);
    }

    // Layer 4: 16 -> 8, ReLU
    float h4[D4];
    #pragma unroll
    for (int j = 0; j < D4; ++j) {
        float acc = b4[j];
        #pragma unroll
        for (int k = 0; k < D3; ++k)
            acc = fmaf(h3[k], w4[j * D3 + k], acc);
        h4[j] = fmaxf(acc, 0.0f);
    }

    // Layer 5: 8 -> 2 (no ReLU)
    float o[D5];
    #pragma unroll
    for (int j = 0; j < D5; ++j) {
        float acc = b5[j];
        #pragma unroll
        for (int k = 0; k < D4; ++k)
            acc = fmaf(h4[k], w5[j * D4 + k], acc);
        o[j] = acc;
    }

    // Store (2 floats per row; row*8 bytes -> float2-aligned).
    *reinterpret_cast<float2*>(out + (long long)row * D5) = make_float2(o[0], o[1]);
}

extern "C" void kernel_launch(void* const* d_in, const int* in_sizes, int n_in,
                              void* d_out, int out_size, void* d_ws, size_t ws_size,
                              hipStream_t stream) {
    const float* x  = (const float*)d_in[0];
    const float* w1 = (const float*)d_in[1];
    const float* b1 = (const float*)d_in[2];
    const float* w2 = (const float*)d_in[3];
    const float* b2 = (const float*)d_in[4];
    const float* w3 = (const float*)d_in[5];
    const float* b3 = (const float*)d_in[6];
    const float* w4 = (const float*)d_in[7];
    const float* b4 = (const float*)d_in[8];
    const float* w5 = (const float*)d_in[9];
    const float* b5 = (const float*)d_in[10];
    float* out = (float*)d_out;

    const int n = in_sizes[0] / D0;  // 1,000,000 rows
    const int block = 256;
    const int grid = (n + block - 1) / block;

    mlp_fused_kernel<<<grid, block, 0, stream>>>(
        x, w1, b1, w2, b2, w3, b3, w4, b4, w5, b5, out, n);
}

// Round 2
// 47.093 us; speedup vs baseline: 3.4617x; 3.4617x over previous
//
#include <hip/hip_runtime.h>

// 5-layer MLP 30->64->32->16->8->2 with ReLU, via bf16 MFMA (16x16x32).
// Activations kept transposed [neuron][batch], batch tile N=16.
// Every layer: D = A(weights) x B(activations). Weight A-fragments built once
// per wave. Inter-layer fragment redistribution via per-wave LDS scratch
// (DS ops from a single wave are processed in order -> no barriers needed).
//
// k-slot mapping used EVERYWHERE (A and B): slot i (0..7) of lane group g:
//   k = 4*g + (i&3) + 16*(i>>2)
// Correctness does not depend on this matching hardware exactly, only on A and
// B using the same map (hardware pairs A-slot j with B-slot j).
// C/D layout (m89-verified): lane l holds D[m][n], n = l&15, m = 4*(l>>4)+q.

typedef float        f32x4 __attribute__((ext_vector_type(4)));
typedef unsigned int u32x4 __attribute__((ext_vector_type(4)));
typedef short        s16x8 __attribute__((ext_vector_type(8)));

static __device__ __forceinline__ unsigned short f2bf(float f) {
    return __builtin_bit_cast(unsigned short, (__bf16)f);
}
static __device__ __forceinline__ unsigned int pkbf(float a, float b) {
    return (unsigned int)f2bf(a) | ((unsigned int)f2bf(b) << 16);
}
static __device__ __forceinline__ unsigned int rp2(float a, float b) {
    return pkbf(fmaxf(a, 0.0f), fmaxf(b, 0.0f));
}

#define MFMA(A, B, C) __builtin_amdgcn_mfma_f32_16x16x32_bf16((A), (B), (C), 0, 0, 0)

__global__ __launch_bounds__(256) void mlp_mfma_kernel(
    const float* __restrict__ x,
    const float* __restrict__ w1, const float* __restrict__ b1,
    const float* __restrict__ w2, const float* __restrict__ b2,
    const float* __restrict__ w3, const float* __restrict__ b3,
    const float* __restrict__ w4, const float* __restrict__ b4,
    const float* __restrict__ w5, const float* __restrict__ b5,
    float* __restrict__ out, int n)
{
    __shared__ unsigned int lds_buf[4][512];   // 2 KB scratch per wave

    const int lane = threadIdx.x & 63;
    const int wv   = threadIdx.x >> 6;
    const int g    = lane >> 4;
    const int ml   = lane & 15;
    unsigned int* H = lds_buf[wv];

    // ---------------- per-wave weight / bias fragment build ----------------
    s16x8 A1[4], A2[2][2], A3, A4, A5;
    #pragma unroll
    for (int t = 0; t < 4; ++t) {
        #pragma unroll
        for (int i = 0; i < 8; ++i) {
            const int k = 4*g + (i & 3) + ((i >> 2) << 4);
            const int m = 16*t + ml;
            float v = (k < 30) ? w1[m*30 + k] : ((k == 30) ? b1[m] : 0.0f);
            A1[t][i] = (short)f2bf(v);
        }
    }
    #pragma unroll
    for (int t = 0; t < 2; ++t)
        #pragma unroll
        for (int s = 0; s < 2; ++s)
            #pragma unroll
            for (int i = 0; i < 8; ++i) {
                const int k = 4*g + (i & 3) + ((i >> 2) << 4);
                A2[t][s][i] = (short)f2bf(w2[(16*t + ml)*64 + 32*s + k]);
            }
    #pragma unroll
    for (int i = 0; i < 8; ++i) {
        const int k = 4*g + (i & 3) + ((i >> 2) << 4);
        A3[i] = (short)f2bf(w3[ml*32 + k]);
        float v4 = 0.0f, v5 = 0.0f;
        if (ml < 8) v4 = (k < 16) ? w4[ml*16 + k] : ((k == 16) ? b4[ml] : 0.0f);
        if (ml < 2) v5 = (k <  8) ? w5[ml*8  + k] : ((k ==  8) ? b5[ml] : 0.0f);
        A4[i] = (short)f2bf(v4);
        A5[i] = (short)f2bf(v5);
    }
    f32x4 bias2[2], bias3;
    #pragma unroll
    for (int t = 0; t < 2; ++t)
        #pragma unroll
        for (int q = 0; q < 4; ++q)
            bias2[t][q] = b2[16*t + 4*g + q];
    #pragma unroll
    for (int q = 0; q < 4; ++q)
        bias3[q] = b3[4*g + q];

    // ---------------- batch-tile loop (grid-stride by wave) ----------------
    const int ntiles = (n + 15) >> 4;
    const int nwaves = gridDim.x * 4;
    int tile = blockIdx.x * 4 + wv;
    if (tile >= ntiles) return;

    auto loadx = [&](int t, f32x4& xa, f32x4& xb) {
        int row = t*16 + ml;
        if (row >= n) row = n - 1;
        const float* rp = x + (size_t)row * 30;     // rows are 8B-aligned
        float2 a01 = *(const float2*)(rp + 4*g);
        float2 a23 = *(const float2*)(rp + 4*g + 2);
        xa[0] = a01.x; xa[1] = a01.y; xa[2] = a23.x; xa[3] = a23.y;
        if (g < 3) {
            float2 b01 = *(const float2*)(rp + 16 + 4*g);
            float2 b23 = *(const float2*)(rp + 18 + 4*g);
            xb[0] = b01.x; xb[1] = b01.y; xb[2] = b23.x; xb[3] = b23.y;
        } else {
            float2 b01 = *(const float2*)(rp + 28);
            xb[0] = b01.x; xb[1] = b01.y;
            xb[2] = 1.0f;   // k==30 slot multiplies the b1 column of W1
            xb[3] = 0.0f;   // k==31 pad
        }
    };

    f32x4 xa, xb;
    loadx(tile, xa, xb);

    const f32x4 zero = {0.0f, 0.0f, 0.0f, 0.0f};

    while (true) {
        const int nt = tile + nwaves;
        const bool have_next = (nt < ntiles);
        f32x4 nxa, nxb;
        if (have_next) loadx(nt, nxa, nxb);   // prefetch next tile's x

        // ---- layer 1: 30(+bias)->64 ----
        u32x4 u0;
        u0.x = pkbf(xa[0], xa[1]); u0.y = pkbf(xa[2], xa[3]);
        u0.z = pkbf(xb[0], xb[1]); u0.w = pkbf(xb[2], xb[3]);
        s16x8 B0 = __builtin_bit_cast(s16x8, u0);
        f32x4 c1[4];
        #pragma unroll
        for (int t = 0; t < 4; ++t) c1[t] = MFMA(A1[t], B0, zero);

        asm volatile("" ::: "memory");
        #pragma unroll
        for (int t = 0; t < 4; ++t) {
            const int p = 8*t + 2*g;
            H[p*16 + ml]       = rp2(c1[t][0], c1[t][1]);
            H[(p + 1)*16 + ml] = rp2(c1[t][2], c1[t][3]);
        }
        asm volatile("" ::: "memory");

        // ---- layer 2: 64->32 (K = 2 steps) ----
        s16x8 B1[2];
        #pragma unroll
        for (int s = 0; s < 2; ++s) {
            const int b = (16*s + 2*g)*16 + ml;
            u32x4 u; u.x = H[b]; u.y = H[b + 16]; u.z = H[b + 128]; u.w = H[b + 144];
            B1[s] = __builtin_bit_cast(s16x8, u);
        }
        asm volatile("" ::: "memory");
        f32x4 c2[2];
        #pragma unroll
        for (int t = 0; t < 2; ++t) {
            f32x4 a = bias2[t];
            #pragma unroll
            for (int s = 0; s < 2; ++s) a = MFMA(A2[t][s], B1[s], a);
            c2[t] = a;
        }
        #pragma unroll
        for (int t = 0; t < 2; ++t) {
            const int p = 8*t + 2*g;
            H[p*16 + ml]       = rp2(c2[t][0], c2[t][1]);
            H[(p + 1)*16 + ml] = rp2(c2[t][2], c2[t][3]);
        }
        asm volatile("" ::: "memory");

        // ---- layer 3: 32->16 ----
        s16x8 B2;
        {
            const int b = (2*g)*16 + ml;
            u32x4 u; u.x = H[b]; u.y = H[b + 16]; u.z = H[b + 128]; u.w = H[b + 144];
            B2 = __builtin_bit_cast(s16x8, u);
        }
        asm volatile("" ::: "memory");
        f32x4 c3 = MFMA(A3, B2, bias3);
        H[(2*g)*16 + ml]     = rp2(c3[0], c3[1]);
        H[(2*g + 1)*16 + ml] = rp2(c3[2], c3[3]);
        asm volatile("" ::: "memory");

        // ---- layer 4: 16(+bias)->8 ----
        s16x8 B3;
        {
            const int b = (2*g)*16 + ml;
            u32x4 u; u.x = H[b]; u.y = H[b + 16];
            u.z = (g == 0) ? 0x3F80u : 0u;   // k==16 slot = 1.0 (bias), rest 0
            u.w = 0u;
            B3 = __builtin_bit_cast(s16x8, u);
        }
        asm volatile("" ::: "memory");
        f32x4 c4 = MFMA(A4, B3, zero);
        H[(2*g)*16 + ml]     = rp2(c4[0], c4[1]);
        H[(2*g + 1)*16 + ml] = rp2(c4[2], c4[3]);
        asm volatile("" ::: "memory");

        // ---- layer 5: 8(+bias)->2 (no ReLU) ----
        s16x8 B4;
        {
            const int b = (2*g)*16 + ml;
            unsigned d0 = H[b], d1 = H[b + 16];
            u32x4 u;
            u.x = (g < 2) ? d0 : ((g == 2) ? 0x3F80u : 0u);  // k==8 slot = 1.0
            u.y = (g < 2) ? d1 : 0u;
            u.z = 0u; u.w = 0u;
            B4 = __builtin_bit_cast(s16x8, u);
        }
        f32x4 c5 = MFMA(A5, B4, zero);

        const int orow = tile*16 + lane;      // lanes 0..15: m=0 -> c5[0], m=1 -> c5[1]
        if (lane < 16 && orow < n) {
            float2 o; o.x = c5[0]; o.y = c5[1];
            *(float2*)(out + (size_t)orow * 2) = o;
        }

        if (!have_next) break;
        xa = nxa; xb = nxb; tile = nt;
    }
}

extern "C" void kernel_launch(void* const* d_in, const int* in_sizes, int n_in,
                              void* d_out, int out_size, void* d_ws, size_t ws_size,
                              hipStream_t stream) {
    const float* x  = (const float*)d_in[0];
    const float* w1 = (const float*)d_in[1];
    const float* b1 = (const float*)d_in[2];
    const float* w2 = (const float*)d_in[3];
    const float* b2 = (const float*)d_in[4];
    const float* w3 = (const float*)d_in[5];
    const float* b3 = (const float*)d_in[6];
    const float* w4 = (const float*)d_in[7];
    const float* b4 = (const float*)d_in[8];
    const float* w5 = (const float*)d_in[9];
    const float* b5 = (const float*)d_in[10];
    float* out = (float*)d_out;

    const int n = in_sizes[0] / 30;           // 1,000,000 rows
    const int ntiles = (n + 15) >> 4;
    int blocks = (ntiles + 3) / 4;
    if (blocks > 1024) blocks = 1024;

    mlp_mfma_kernel<<<blocks, 256, 0, stream>>>(
        x, w1, b1, w2, b2, w3, b3, w4, b4, w5, b5, out, n);
}